// Round 11
// baseline (1360.801 us; speedup 1.0000x reference)
//
#include <hip/hip_runtime.h>
#include <stdint.h>
#include <math.h>

typedef __bf16 bf16;
typedef __attribute__((ext_vector_type(8))) __bf16 bf16x8;
typedef __attribute__((ext_vector_type(16))) float f32x16;

// ---------- setup: A_gcn (gmat[0..15]) and M_sage (gmat[16..31]) -----------
__global__ void k_setup(const int* __restrict__ ei, float* __restrict__ gmat) {
    if (threadIdx.x != 0 || blockIdx.x != 0) return;
    bool is64 = true;
    for (int i = 0; i < 12; i++) if (ei[2 * i + 1] != 0) { is64 = false; break; }
    int src[12], dst[12];
    for (int e = 0; e < 12; e++) {
        if (is64) { src[e] = ei[2 * e]; dst[e] = ei[24 + 2 * e]; }
        else      { src[e] = ei[e];     dst[e] = ei[12 + e]; }
    }
    float deg[4] = {1.f, 1.f, 1.f, 1.f};
    for (int e = 0; e < 12; e++) deg[dst[e]] += 1.f;
    float dinv[4];
    for (int n = 0; n < 4; n++) dinv[n] = 1.f / sqrtf(deg[n]);
    float A[16];
    for (int i = 0; i < 16; i++) A[i] = 0.f;
    for (int e = 0; e < 12; e++) A[dst[e] * 4 + src[e]] += dinv[src[e]] * dinv[dst[e]];
    for (int n = 0; n < 4; n++) A[n * 4 + n] += dinv[n] * dinv[n];
    float cnt[4] = {0.f, 0.f, 0.f, 0.f};
    for (int e = 0; e < 12; e++) cnt[dst[e]] += 1.f;
    for (int n = 0; n < 4; n++) cnt[n] = fmaxf(cnt[n], 1.f);
    float Mm[16];
    for (int i = 0; i < 16; i++) Mm[i] = 0.f;
    for (int e = 0; e < 12; e++) Mm[dst[e] * 4 + src[e]] += 1.f;
    for (int n = 0; n < 4; n++)
        for (int m = 0; m < 4; m++) Mm[n * 4 + m] /= cnt[n];
    for (int i = 0; i < 16; i++) { gmat[i] = A[i]; gmat[16 + i] = Mm[i]; }
}

// ---------- Wt1: transpose W [K,N] -> Bt [N,K] bf16 ------------------------
__global__ __launch_bounds__(256) void wtrans(const float* __restrict__ W, int K,
                                              int N, bf16* __restrict__ Wt) {
    int idx = blockIdx.x * 256 + threadIdx.x;
    if (idx >= N * K) return;
    int n = idx / K, k = idx - n * K;
    Wt[idx] = (bf16)W[(size_t)k * N + n];
}

// ---------- interleaved stack: Bt[2F,K]; row 2f -> Wl col f, 2f+1 -> Wr ----
__global__ __launch_bounds__(256) void wtransI(const float* __restrict__ Wl,
                                               const float* __restrict__ Wr,
                                               int K, int F, bf16* __restrict__ Bt) {
    int idx = blockIdx.x * 256 + threadIdx.x;
    if (idx >= 2 * F * K) return;
    int n = idx / K, k = idx - n * K;
    int f = n >> 1;
    float v = (n & 1) ? Wr[(size_t)k * F + f] : Wl[(size_t)k * F + f];
    Bt[idx] = (bf16)v;
}

// ---------- cast fp32 x -> bf16 --------------------------------------------
__global__ __launch_bounds__(256) void cast_x(const float4* __restrict__ x,
                                              bf16x8* __restrict__ out) {
    int i = blockIdx.x * 256 + threadIdx.x;
    float4 a = x[2 * i], b = x[2 * i + 1];
    bf16x8 o;
    o[0] = (bf16)a.x; o[1] = (bf16)a.y; o[2] = (bf16)a.z; o[3] = (bf16)a.w;
    o[4] = (bf16)b.x; o[5] = (bf16)b.y; o[6] = (bf16)b.z; o[7] = (bf16)b.w;
    out[i] = o;
}

// ---------- zero ssq accumulators ------------------------------------------
__global__ __launch_bounds__(256) void k_zero(float4* __restrict__ p, int n4) {
    int i = blockIdx.x * 256 + threadIdx.x;
    if (i < n4) p[i] = make_float4(0.f, 0.f, 0.f, 0.f);
}

// ---------- MFMA GEMM, 128x256 tile, BK=64, 32x32x16 bf16 ------------------
// A: register pipeline -> ds_write -> LDS (sA only, 16 KB); A(i+1) global
// loads issue right after barrier 1 and drain at the next iter's ds_write,
// overlapping HBM latency with the MFMA section.  B: NO LDS — fragment-
// ordered Wt means each lane's B frag is a contiguous 16B global load
// (L2-resident weights), software-pipelined one k-slot ahead.
// All ordering: plain loads + register deps + __syncthreads (verified).
// mode 1 (GCN): out = mix4(A@Bt^T)+bias, ReLU.
// mode 2 (SAGE, Bt interleaved [Wl|Wr]): h_un[M,F=N/2] + atomic per-row ssq.
__global__ __launch_bounds__(256, 2) void gemm_mfma(
    const bf16* __restrict__ A, int K,
    const bf16* __restrict__ Bt,
    const float* __restrict__ bias,
    bf16* __restrict__ out, int N, int mode,
    const float* __restrict__ gm, float* __restrict__ ssq) {
    __shared__ bf16 sA[8192];    // 16 slots (kslot s*4 + rowblk) x 512 (32r x 16k)
    const int t = threadIdx.x;
    const int lane = t & 63;
    const int w = t >> 6;
    const int wr = w >> 1, wc = w & 1;
    // XCD-aware swizzle (requires gridDim.y % 8 == 0)
    const int lin = blockIdx.x + gridDim.x * blockIdx.y;
    const int C = gridDim.x;
    const int cls = lin & 7;
    const int s0 = lin >> 3;
    const int rpc = gridDim.y >> 3;
    const int sy = s0 / C;
    const int row0 = (cls * rpc + sy) * 128;
    const int col0 = (s0 - sy * C) * 256;
    const int m32 = lane & 31;   // m (or n) within 32x32 fragment
    const int kh = lane >> 5;    // k-half within 16-k slot: k = kh*8 + j

    f32x16 acc[2][4] = {};

    const size_t rA = (size_t)(row0 + w * 32 + m32) * K;
    size_t rB[4];
#pragma unroll
    for (int j = 0; j < 4; j++)
        rB[j] = (size_t)(col0 + (4 * wc + j) * 32 + m32) * K + kh * 8;
    const int kaBase = kh * 8;
    const int iters = K >> 6;

    // prologue: A(0) and B(0, slot 0) into registers
    bf16x8 an[4], b0[4], bc[4], bn[4];
#pragma unroll
    for (int s = 0; s < 4; s++) an[s] = *(const bf16x8*)(A + rA + kaBase + s * 16);
#pragma unroll
    for (int j = 0; j < 4; j++) b0[j] = *(const bf16x8*)(Bt + rB[j]);

    for (int i = 0; i < iters; i++) {
        // stage tile-i A (regs -> LDS); vmcnt dep on an[] resolved long ago
#pragma unroll
        for (int s = 0; s < 4; s++)
            *(bf16x8*)&sA[(s * 4 + w) * 512 + lane * 8] = an[s];
        __syncthreads();
        const int ip1 = i + 1;
        if (ip1 < iters) {
            int ka = ip1 * 64 + kaBase;
#pragma unroll
            for (int s = 0; s < 4; s++)
                an[s] = *(const bf16x8*)(A + rA + ka + s * 16);
        }
#pragma unroll
        for (int j = 0; j < 4; j++) bc[j] = b0[j];
#pragma unroll
        for (int s = 0; s < 4; s++) {
            // issue next B slot (or next iter's slot 0) before this slot's MFMAs
            if (s < 3) {
                int kb = i * 64 + (s + 1) * 16;
#pragma unroll
                for (int j = 0; j < 4; j++)
                    bn[j] = *(const bf16x8*)(Bt + rB[j] + kb);
            } else if (ip1 < iters) {
#pragma unroll
                for (int j = 0; j < 4; j++)
                    b0[j] = *(const bf16x8*)(Bt + rB[j] + ip1 * 64);
            }
            bf16x8 af[2];
#pragma unroll
            for (int ii = 0; ii < 2; ii++)
                af[ii] = *(const bf16x8*)&sA[(s * 4 + 2 * wr + ii) * 512 + lane * 8];
#pragma unroll
            for (int ii = 0; ii < 2; ii++)
#pragma unroll
                for (int j = 0; j < 4; j++)
                    acc[ii][j] = __builtin_amdgcn_mfma_f32_32x32x16_bf16(af[ii], bc[j], acc[ii][j], 0, 0, 0);
            if (s < 3) {
#pragma unroll
                for (int j = 0; j < 4; j++) bc[j] = bn[j];
            }
        }
        __syncthreads();
    }

    float g[16];
#pragma unroll
    for (int q = 0; q < 16; q++) g[q] = gm[q];

    if (mode == 1) {
        // GCN: in-register 4x4 node mix per reg-quad + bias + ReLU
#pragma unroll
        for (int i = 0; i < 2; i++) {
            int rb = row0 + (2 * wr + i) * 32 + 4 * kh;
#pragma unroll
            for (int j = 0; j < 4; j++) {
                int c = col0 + (4 * wc + j) * 32 + m32;
                float bsv = bias[c];
#pragma unroll
                for (int q = 0; q < 4; q++) {
#pragma unroll
                    for (int n = 0; n < 4; n++) {
                        float v = g[n * 4 + 0] * acc[i][j][q * 4 + 0] +
                                  g[n * 4 + 1] * acc[i][j][q * 4 + 1] +
                                  g[n * 4 + 2] * acc[i][j][q * 4 + 2] +
                                  g[n * 4 + 3] * acc[i][j][q * 4 + 3] + bsv;
                        out[(size_t)(rb + 8 * q + n) * N + c] = (bf16)fmaxf(v, 0.f);
                    }
                }
            }
        }
    } else {
        // SAGE: even m32 lane = Wl col f (mix), odd = Wr col f (self)
        const int F = N >> 1;
        const bool ev = ((m32 & 1) == 0);
#pragma unroll
        for (int i = 0; i < 2; i++) {
            int rb = row0 + (2 * wr + i) * 32 + 4 * kh;
#pragma unroll
            for (int q = 0; q < 4; q++) {
                float ssql[4] = {0.f, 0.f, 0.f, 0.f};
#pragma unroll
                for (int j = 0; j < 4; j++) {
                    int c = col0 + (4 * wc + j) * 32 + m32;
                    int f = c >> 1;
                    float bsv = bias[f];
                    float mine[4];
                    if (ev) {
#pragma unroll
                        for (int n = 0; n < 4; n++)
                            mine[n] = g[n * 4 + 0] * acc[i][j][q * 4 + 0] +
                                      g[n * 4 + 1] * acc[i][j][q * 4 + 1] +
                                      g[n * 4 + 2] * acc[i][j][q * 4 + 2] +
                                      g[n * 4 + 3] * acc[i][j][q * 4 + 3];
                    } else {
#pragma unroll
                        for (int n = 0; n < 4; n++) mine[n] = acc[i][j][q * 4 + n];
                    }
#pragma unroll
                    for (int n = 0; n < 4; n++) {
                        float oth = __shfl_xor(mine[n], 1);
                        float tot = mine[n] + oth + bsv;
                        ssql[n] += tot * tot;
                        if (ev) out[(size_t)(rb + 8 * q + n) * F + f] = (bf16)tot;
                    }
                }
                // reduce over the 32-lane m32 group (pairs duplicate -> x0.5)
#pragma unroll
                for (int n = 0; n < 4; n++) {
                    float v = ssql[n];
                    v += __shfl_xor(v, 1); v += __shfl_xor(v, 2);
                    v += __shfl_xor(v, 4); v += __shfl_xor(v, 8);
                    v += __shfl_xor(v, 16);
                    ssql[n] = v;
                }
                if (m32 == 0) {
#pragma unroll
                    for (int n = 0; n < 4; n++)
                        atomicAdd(&ssq[rb + 8 * q + n], ssql[n] * 0.5f);
                }
            }
        }
    }
}

// ---------- apply L2-norm (from ssq) + ReLU, in place ----------------------
__global__ __launch_bounds__(256) void norm_apply(bf16x8* __restrict__ h,
                                                  const float* __restrict__ ssq,
                                                  int shift) {
    int idx = blockIdx.x * 256 + threadIdx.x;
    int row = idx >> shift;
    float inv = 1.f / fmaxf(sqrtf(ssq[row]), 1e-12f);
    bf16x8 v = h[idx], o;
#pragma unroll
    for (int c = 0; c < 8; c++) o[c] = (bf16)fmaxf((float)v[c] * inv, 0.f);
    h[idx] = o;
}

// ---------- final FC (1024 -> 10) + softmax, fused h4 norm+ReLU ------------
__global__ __launch_bounds__(256) void fc_softmax(const bf16x8* __restrict__ h,
                                                  const float* __restrict__ ssq4,
                                                  const float* __restrict__ Wfc,
                                                  const float* __restrict__ bfc,
                                                  float* __restrict__ outp) {
    __shared__ float WT[10][1024];
    int t = threadIdx.x;
    for (int i = t; i < 10240; i += 256) { int o = i % 10, k = i / 10; WT[o][k] = Wfc[i]; }
    __syncthreads();
    int wid = t >> 6, lane = t & 63;
    size_t e = (size_t)blockIdx.x * 4 + wid;
    const bf16x8* hp = h + e * 128;
    float acc[10];
#pragma unroll
    for (int o = 0; o < 10; o++) acc[o] = 0.f;
#pragma unroll
    for (int j = 0; j < 2; j++) {
        int ch = j * 64 + lane;
        int node = ch >> 5;                       // 32 chunks per 256-feat node row
        float inv = 1.f / fmaxf(sqrtf(ssq4[e * 4 + node]), 1e-12f);
        bf16x8 v = hp[ch];
        float f[8];
#pragma unroll
        for (int c = 0; c < 8; c++) f[c] = fmaxf((float)v[c] * inv, 0.f);
        int k0 = ch * 8;
#pragma unroll
        for (int o = 0; o < 10; o++) {
            const float* wr = &WT[o][k0];
            float s = 0.f;
#pragma unroll
            for (int c = 0; c < 8; c++) s += f[c] * wr[c];
            acc[o] += s;
        }
    }
#pragma unroll
    for (int o = 0; o < 10; o++) {
        float v = acc[o];
        v += __shfl_xor(v, 32); v += __shfl_xor(v, 16); v += __shfl_xor(v, 8);
        v += __shfl_xor(v, 4);  v += __shfl_xor(v, 2);  v += __shfl_xor(v, 1);
        acc[o] = v + bfc[o];
    }
    float mx = acc[0];
#pragma unroll
    for (int o = 1; o < 10; o++) mx = fmaxf(mx, acc[o]);
    float sum = 0.f, p[10];
#pragma unroll
    for (int o = 0; o < 10; o++) { p[o] = expf(acc[o] - mx); sum += p[o]; }
    float inv = 1.f / sum;
    if (lane < 10) outp[e * 10 + lane] = p[lane] * inv;
}

// ---------------------------------------------------------------------------
extern "C" void kernel_launch(void* const* d_in, const int* in_sizes, int n_in,
                              void* d_out, int out_size, void* d_ws, size_t ws_size,
                              hipStream_t stream) {
    const float* x   = (const float*)d_in[0];
    const int*   ei  = (const int*)d_in[1];
    const float* W1  = (const float*)d_in[2];
    const float* b1  = (const float*)d_in[3];
    const float* Wl2 = (const float*)d_in[4];
    const float* bl2 = (const float*)d_in[5];
    const float* Wr2 = (const float*)d_in[6];
    const float* Wl3 = (const float*)d_in[7];
    const float* bl3 = (const float*)d_in[8];
    const float* Wr3 = (const float*)d_in[9];
    const float* Wl4 = (const float*)d_in[10];
    const float* bl4 = (const float*)d_in[11];
    const float* Wr4 = (const float*)d_in[12];
    const float* Wfc = (const float*)d_in[13];
    const float* bfc = (const float*)d_in[14];
    float* out = (float*)d_out;

    const int B = 32768;
    char* base = (char*)d_ws;
    float* gmat = (float*)base;
    bf16* Wt1 = (bf16*)(base + 4096);                  // [1024 x 64]
    bf16* Wt2 = Wt1 + 1024 * 64;                       // [1024 x 1024] interleaved Wl2/Wr2
    bf16* Wt3 = Wt2 + 1024 * 1024;                     // [512 x 512]  interleaved
    bf16* Wt4 = Wt3 + 512 * 512;                       // [512 x 256]  interleaved
    char* sl  = (char*)(Wt4 + 512 * 256);
    size_t fixed = (size_t)(sl - base);

    // per-elem: R0 512B + R1 8192B + R2 4096B + ssq 48B = 12848 B
    int Bs = B;
    while (Bs > 512 && fixed + (size_t)Bs * 12848 > ws_size) Bs >>= 1;
    int nslice = B / Bs;
    int M = Bs * 4;

    bf16* R0 = (bf16*)sl;                       // xb  [M,64]
    bf16* R1 = R0 + (size_t)Bs * 256;           // h1 [M,1024]; then h3_un [M,256]
    bf16* R2 = R1 + (size_t)Bs * 4096;          // h2_un [M,512]; then h4_un [M,256]
    float* ssqb = (float*)(R2 + (size_t)Bs * 2048);   // 3*M floats

    hipLaunchKernelGGL(k_setup, dim3(1), dim3(64), 0, stream, ei, gmat);
    hipLaunchKernelGGL(wtrans, dim3((1024 * 64 + 255) / 256), dim3(256), 0, stream,
                       W1, 64, 1024, Wt1);
    hipLaunchKernelGGL(wtransI, dim3((1024 * 1024 + 255) / 256), dim3(256), 0, stream,
                       Wl2, Wr2, 1024, 512, Wt2);
    hipLaunchKernelGGL(wtransI, dim3((512 * 512 + 255) / 256), dim3(256), 0, stream,
                       Wl3, Wr3, 512, 256, Wt3);
    hipLaunchKernelGGL(wtransI, dim3((512 * 256 + 255) / 256), dim3(256), 0, stream,
                       Wl4, Wr4, 256, 256, Wt4);

    for (int s = 0; s < nslice; s++) {
        const float* xs = x + (size_t)s * Bs * 256;
        hipLaunchKernelGGL(k_zero, dim3((3 * M / 4 + 255) / 256), dim3(256), 0, stream,
                           (float4*)ssqb, 3 * M / 4);
        hipLaunchKernelGGL(cast_x, dim3(Bs / 8), dim3(256), 0, stream,
                           (const float4*)xs, (bf16x8*)R0);
        // L1 GCN: h1 = relu(mix(x@W1) + b1)   [mode 1]  N=1024, K=64
        hipLaunchKernelGGL(gemm_mfma, dim3(4, M / 128), dim3(256), 0, stream,
                           R0, 64, Wt1, b1, R1, 1024, 1, gmat, (float*)nullptr);
        // L2 SAGE: h2_un (F=512) + ssq  [mode 2]  N=1024, K=1024
        hipLaunchKernelGGL(gemm_mfma, dim3(4, M / 128), dim3(256), 0, stream,
                           R1, 1024, Wt2, bl2, R2, 1024, 2, gmat + 16, ssqb);
        hipLaunchKernelGGL(norm_apply, dim3(M / 4), dim3(256), 0, stream,
                           (bf16x8*)R2, ssqb, 6);
        // L3 SAGE: h3_un (F=256) into R1   N=512, K=512
        hipLaunchKernelGGL(gemm_mfma, dim3(2, M / 128), dim3(256), 0, stream,
                           R2, 512, Wt3, bl3, R1, 512, 2, gmat + 16, ssqb + M);
        hipLaunchKernelGGL(norm_apply, dim3(M / 8), dim3(256), 0, stream,
                           (bf16x8*)R1, ssqb + M, 5);
        // L4 SAGE: h4_un (F=256) into R2   N=512, K=256
        hipLaunchKernelGGL(gemm_mfma, dim3(2, M / 128), dim3(256), 0, stream,
                           R1, 256, Wt4, bl4, R2, 512, 2, gmat + 16, ssqb + 2 * M);
        // FC + softmax with fused h4 norm+ReLU
        hipLaunchKernelGGL(fc_softmax, dim3(Bs / 4), dim3(256), 0, stream,
                           (const bf16x8*)R2, ssqb + 2 * M, Wfc, bfc,
                           out + (size_t)s * Bs * 10);
    }
}

// Round 13
// 944.553 us; speedup vs baseline: 1.4407x; 1.4407x over previous
//
#include <hip/hip_runtime.h>
#include <stdint.h>
#include <math.h>

typedef __bf16 bf16;
typedef __attribute__((ext_vector_type(8))) __bf16 bf16x8;
typedef __attribute__((ext_vector_type(16))) float f32x16;

#define AS1 __attribute__((address_space(1)))
#define AS3 __attribute__((address_space(3)))

__device__ __forceinline__ void glds16(const void* g, void* l) {
    __builtin_amdgcn_global_load_lds((const AS1 uint32_t*)g, (AS3 uint32_t*)l, 16, 0, 0);
}

// Fragment-tile (FT) layout for X[M,K]: tile (rb=r>>5, ks=k>>4) is 512 elems:
// addr = (rb*(K/16)+ks)*512 + (((k>>3)&1)*32 + (r&31))*8 + (k&7).
// A wave's MFMA fragment = 1KB contiguous -> coalesced staging loads.

// ---------- setup: A_gcn (gmat[0..15]) and M_sage (gmat[16..31]) -----------
__global__ void k_setup(const int* __restrict__ ei, float* __restrict__ gmat) {
    if (threadIdx.x != 0 || blockIdx.x != 0) return;
    bool is64 = true;
    for (int i = 0; i < 12; i++) if (ei[2 * i + 1] != 0) { is64 = false; break; }
    int src[12], dst[12];
    for (int e = 0; e < 12; e++) {
        if (is64) { src[e] = ei[2 * e]; dst[e] = ei[24 + 2 * e]; }
        else      { src[e] = ei[e];     dst[e] = ei[12 + e]; }
    }
    float deg[4] = {1.f, 1.f, 1.f, 1.f};
    for (int e = 0; e < 12; e++) deg[dst[e]] += 1.f;
    float dinv[4];
    for (int n = 0; n < 4; n++) dinv[n] = 1.f / sqrtf(deg[n]);
    float A[16];
    for (int i = 0; i < 16; i++) A[i] = 0.f;
    for (int e = 0; e < 12; e++) A[dst[e] * 4 + src[e]] += dinv[src[e]] * dinv[dst[e]];
    for (int n = 0; n < 4; n++) A[n * 4 + n] += dinv[n] * dinv[n];
    float cnt[4] = {0.f, 0.f, 0.f, 0.f};
    for (int e = 0; e < 12; e++) cnt[dst[e]] += 1.f;
    for (int n = 0; n < 4; n++) cnt[n] = fmaxf(cnt[n], 1.f);
    float Mm[16];
    for (int i = 0; i < 16; i++) Mm[i] = 0.f;
    for (int e = 0; e < 12; e++) Mm[dst[e] * 4 + src[e]] += 1.f;
    for (int n = 0; n < 4; n++)
        for (int m = 0; m < 4; m++) Mm[n * 4 + m] /= cnt[n];
    for (int i = 0; i < 16; i++) { gmat[i] = A[i]; gmat[16 + i] = Mm[i]; }
}

// ---------- W [K,N] -> Wt FT[N,K] bf16 -------------------------------------
__global__ __launch_bounds__(256) void wtransF(const float* __restrict__ W, int K,
                                               int N, bf16* __restrict__ Wt) {
    int a = blockIdx.x * 256 + threadIdx.x;
    if (a >= N * K) return;
    int j = a & 7, c64 = (a >> 3) & 63, tile = a >> 9;
    int m32 = c64 & 31, kh = c64 >> 5;
    int TK = K >> 4;
    int rblk = tile / TK, ks = tile - rblk * TK;
    int n = rblk * 32 + m32, k = ks * 16 + kh * 8 + j;
    Wt[a] = (bf16)W[(size_t)k * N + n];
}

// ---------- interleaved [Wl|Wr] -> Wt FT[2F,K]; row 2f->Wl, 2f+1->Wr -------
__global__ __launch_bounds__(256) void wtransI(const float* __restrict__ Wl,
                                               const float* __restrict__ Wr,
                                               int K, int F, bf16* __restrict__ Bt) {
    int a = blockIdx.x * 256 + threadIdx.x;
    if (a >= 2 * F * K) return;
    int j = a & 7, c64 = (a >> 3) & 63, tile = a >> 9;
    int m32 = c64 & 31, kh = c64 >> 5;
    int TK = K >> 4;
    int rblk = tile / TK, ks = tile - rblk * TK;
    int n = rblk * 32 + m32, k = ks * 16 + kh * 8 + j;
    int f = n >> 1;
    float v = (n & 1) ? Wr[(size_t)k * F + f] : Wl[(size_t)k * F + f];
    Bt[a] = (bf16)v;
}

// ---------- cast fp32 x [M,64] -> bf16 FT ----------------------------------
__global__ __launch_bounds__(256) void cast_x(const float4* __restrict__ x,
                                              bf16x8* __restrict__ out) {
    int i = blockIdx.x * 256 + threadIdx.x;   // chunk index over M*8
    int c64 = i & 63, m32 = c64 & 31, kh = c64 >> 5;
    int tile = i >> 6, RB = tile >> 2, ks = tile & 3;
    int row = RB * 32 + m32;
    int fb4 = ks * 4 + kh * 2;                // float4 index within 16/row
    float4 a = x[(size_t)row * 16 + fb4], b = x[(size_t)row * 16 + fb4 + 1];
    bf16x8 o;
    o[0] = (bf16)a.x; o[1] = (bf16)a.y; o[2] = (bf16)a.z; o[3] = (bf16)a.w;
    o[4] = (bf16)b.x; o[5] = (bf16)b.y; o[6] = (bf16)b.z; o[7] = (bf16)b.w;
    out[i] = o;
}

// ---------- zero ssq accumulators ------------------------------------------
__global__ __launch_bounds__(256) void k_zero(float4* __restrict__ p, int n4) {
    int i = blockIdx.x * 256 + threadIdx.x;
    if (i < n4) p[i] = make_float4(0.f, 0.f, 0.f, 0.f);
}

// ---------- MFMA GEMM, 128x256 tile, BK=64, 32x32x16 bf16, FT operands -----
// Barrier-staged glds16 + __syncthreads (m97-proven). Both A and Bt are FT ->
// every glds16 reads 1KB contiguous per wave (coalesced; 4x less L2 traffic
// than the stride-K gather). LDS bytes identical to fragment order: 0 conflicts.
// mode 1 (GCN): out = FT(mix4(A@Bt^T)+bias, ReLU) with next-K = N.
// mode 2 (SAGE, interleaved [Wl|Wr]): out = FT(h_un[M,F=N/2]) + atomic ssq.
__global__ __launch_bounds__(256, 2) void gemm_mfma(
    const bf16* __restrict__ A, int K,
    const bf16* __restrict__ Bt,
    const float* __restrict__ bias,
    bf16* __restrict__ out, int N, int mode,
    const float* __restrict__ gm, float* __restrict__ ssq) {
    __shared__ bf16 sA[8192];    // 16 slots (kslot s*4 + rowblk) x 512
    __shared__ bf16 sB[16384];   // 32 slots (kslot s*8 + colblk) x 512
    const int t = threadIdx.x;
    const int lane = t & 63;
    const int w = t >> 6;
    const int wr = w >> 1, wc = w & 1;
    // XCD-aware swizzle (requires gridDim.y % 8 == 0)
    const int lin = blockIdx.x + gridDim.x * blockIdx.y;
    const int C = gridDim.x;
    const int cls = lin & 7;
    const int s0 = lin >> 3;
    const int rpc = gridDim.y >> 3;
    const int sy = s0 / C;
    const int row0 = (cls * rpc + sy) * 128;
    const int col0 = (s0 - sy * C) * 256;
    const int m32 = lane & 31;
    const int kh = lane >> 5;

    f32x16 acc[2][4] = {};

    const int TK = K >> 4;
    const size_t tA  = ((size_t)(row0 >> 5) + w) * TK;
    const size_t tB0 = ((size_t)(col0 >> 5) + w) * TK;
    const size_t tB1 = ((size_t)(col0 >> 5) + w + 4) * TK;
    const int le = lane * 8;

    for (int kb = 0; kb < K; kb += 64) {
        int kt = kb >> 4;
#pragma unroll
        for (int s = 0; s < 4; s++) {
            glds16(A  + (tA  + kt + s) * 512 + le, &sA[(s * 4 + w) * 512]);
            glds16(Bt + (tB0 + kt + s) * 512 + le, &sB[(s * 8 + w) * 512]);
            glds16(Bt + (tB1 + kt + s) * 512 + le, &sB[(s * 8 + w + 4) * 512]);
        }
        __syncthreads();
#pragma unroll
        for (int s = 0; s < 4; s++) {
            bf16x8 af[2], bfr[4];
#pragma unroll
            for (int i = 0; i < 2; i++)
                af[i] = *(const bf16x8*)&sA[(s * 4 + 2 * wr + i) * 512 + le];
#pragma unroll
            for (int j = 0; j < 4; j++)
                bfr[j] = *(const bf16x8*)&sB[(s * 8 + 4 * wc + j) * 512 + le];
#pragma unroll
            for (int i = 0; i < 2; i++)
#pragma unroll
                for (int j = 0; j < 4; j++)
                    acc[i][j] = __builtin_amdgcn_mfma_f32_32x32x16_bf16(af[i], bfr[j], acc[i][j], 0, 0, 0);
        }
        __syncthreads();
    }

    float g[16];
#pragma unroll
    for (int q = 0; q < 16; q++) g[q] = gm[q];

    if (mode == 1) {
        // GCN: node mix per reg-quad + bias + ReLU; write FT (next-K = N)
        const int Tn = N >> 4;
#pragma unroll
        for (int i = 0; i < 2; i++) {
            size_t RBo = (size_t)(row0 >> 5) + 2 * wr + i;
#pragma unroll
            for (int j = 0; j < 4; j++) {
                int c = col0 + (4 * wc + j) * 32 + m32;
                size_t tbase = (RBo * Tn + (c >> 4)) * 512;
                int coff = ((c >> 3) & 1) * 32;
                int cj = c & 7;
                float bsv = bias[c];
#pragma unroll
                for (int q = 0; q < 4; q++) {
#pragma unroll
                    for (int n = 0; n < 4; n++) {
                        float v = g[n * 4 + 0] * acc[i][j][q * 4 + 0] +
                                  g[n * 4 + 1] * acc[i][j][q * 4 + 1] +
                                  g[n * 4 + 2] * acc[i][j][q * 4 + 2] +
                                  g[n * 4 + 3] * acc[i][j][q * 4 + 3] + bsv;
                        out[tbase + (size_t)(coff + 4 * kh + 8 * q + n) * 8 + cj] =
                            (bf16)fmaxf(v, 0.f);
                    }
                }
            }
        }
    } else {
        // SAGE: even m32 = Wl col f (mix), odd = Wr col f (self); write FT(F)
        const int F = N >> 1;
        const int Tf = F >> 4;
        const bool ev = ((m32 & 1) == 0);
#pragma unroll
        for (int i = 0; i < 2; i++) {
            size_t RBo = (size_t)(row0 >> 5) + 2 * wr + i;
            int rbAbs = row0 + (2 * wr + i) * 32 + 4 * kh;
#pragma unroll
            for (int q = 0; q < 4; q++) {
                float ssql[4] = {0.f, 0.f, 0.f, 0.f};
#pragma unroll
                for (int j = 0; j < 4; j++) {
                    int c = col0 + (4 * wc + j) * 32 + m32;
                    int f = c >> 1;
                    size_t tbase = (RBo * Tf + (f >> 4)) * 512;
                    int foff = ((f >> 3) & 1) * 32;
                    int fj = f & 7;
                    float bsv = bias[f];
                    float mine[4];
                    if (ev) {
#pragma unroll
                        for (int n = 0; n < 4; n++)
                            mine[n] = g[n * 4 + 0] * acc[i][j][q * 4 + 0] +
                                      g[n * 4 + 1] * acc[i][j][q * 4 + 1] +
                                      g[n * 4 + 2] * acc[i][j][q * 4 + 2] +
                                      g[n * 4 + 3] * acc[i][j][q * 4 + 3];
                    } else {
#pragma unroll
                        for (int n = 0; n < 4; n++) mine[n] = acc[i][j][q * 4 + n];
                    }
#pragma unroll
                    for (int n = 0; n < 4; n++) {
                        float oth = __shfl_xor(mine[n], 1);
                        float tot = mine[n] + oth + bsv;
                        ssql[n] += tot * tot;
                        if (ev)
                            out[tbase + (size_t)(foff + 4 * kh + 8 * q + n) * 8 + fj] =
                                (bf16)tot;
                    }
                }
#pragma unroll
                for (int n = 0; n < 4; n++) {
                    float v = ssql[n];
                    v += __shfl_xor(v, 1); v += __shfl_xor(v, 2);
                    v += __shfl_xor(v, 4); v += __shfl_xor(v, 8);
                    v += __shfl_xor(v, 16);
                    ssql[n] = v;
                }
                if (m32 == 0) {
#pragma unroll
                    for (int n = 0; n < 4; n++)
                        atomicAdd(&ssq[rbAbs + 8 * q + n], ssql[n] * 0.5f);
                }
            }
        }
    }
}

// ---------- apply L2-norm + ReLU in place, FT layout -----------------------
// chunk idx: tile=idx>>6, row = (tile>>tsh)*32 + (idx&31); tsh = log2(F/16).
__global__ __launch_bounds__(256) void norm_apply(bf16x8* __restrict__ h,
                                                  const float* __restrict__ ssq,
                                                  int tsh) {
    int idx = blockIdx.x * 256 + threadIdx.x;
    int row = (((idx >> 6) >> tsh) << 5) | (idx & 31);
    float inv = 1.f / fmaxf(sqrtf(ssq[row]), 1e-12f);
    bf16x8 v = h[idx], o;
#pragma unroll
    for (int c = 0; c < 8; c++) o[c] = (bf16)fmaxf((float)v[c] * inv, 0.f);
    h[idx] = o;
}

// ---------- final FC (1024->10) + softmax, fused h4 norm+ReLU, FT input ----
// h4 FT[M,256] (T=16). Element e: rows 4e..4e+3 live in row-block e>>3 at
// m32 = 4*(e&7)+node. lane -> (ks=lane&15, node=lane>>4), jj loop = kh.
// FC feature index = node*256 + ks*16 + jj*8 + c  (node offset! R12 bug).
__global__ __launch_bounds__(256) void fc_softmax(const bf16x8* __restrict__ h,
                                                  const float* __restrict__ ssq4,
                                                  const float* __restrict__ Wfc,
                                                  const float* __restrict__ bfc,
                                                  float* __restrict__ outp) {
    __shared__ float WT[10][1024];
    int t = threadIdx.x;
    for (int i = t; i < 10240; i += 256) { int o = i % 10, k = i / 10; WT[o][k] = Wfc[i]; }
    __syncthreads();
    int wid = t >> 6, lane = t & 63;
    size_t e = (size_t)blockIdx.x * 4 + wid;
    size_t eb8 = e >> 3;
    int eo = (int)(e & 7);
    int ks = lane & 15, node = lane >> 4;
    float inv = 1.f / fmaxf(sqrtf(ssq4[e * 4 + node]), 1e-12f);
    float acc[10];
#pragma unroll
    for (int o = 0; o < 10; o++) acc[o] = 0.f;
#pragma unroll
    for (int jj = 0; jj < 2; jj++) {
        size_t ch = (eb8 * 16 + ks) * 64 + jj * 32 + eo * 4 + node;
        bf16x8 v = h[ch];
        float f[8];
#pragma unroll
        for (int c = 0; c < 8; c++) f[c] = fmaxf((float)v[c] * inv, 0.f);
        int k0 = node * 256 + ks * 16 + jj * 8;
#pragma unroll
        for (int o = 0; o < 10; o++) {
            const float* wr = &WT[o][k0];
            float s = 0.f;
#pragma unroll
            for (int c = 0; c < 8; c++) s += f[c] * wr[c];
            acc[o] += s;
        }
    }
#pragma unroll
    for (int o = 0; o < 10; o++) {
        float v = acc[o];
        v += __shfl_xor(v, 32); v += __shfl_xor(v, 16); v += __shfl_xor(v, 8);
        v += __shfl_xor(v, 4);  v += __shfl_xor(v, 2);  v += __shfl_xor(v, 1);
        acc[o] = v + bfc[o];
    }
    float mx = acc[0];
#pragma unroll
    for (int o = 1; o < 10; o++) mx = fmaxf(mx, acc[o]);
    float sum = 0.f, p[10];
#pragma unroll
    for (int o = 0; o < 10; o++) { p[o] = expf(acc[o] - mx); sum += p[o]; }
    float inv2 = 1.f / sum;
    if (lane < 10) outp[e * 10 + lane] = p[lane] * inv2;
}

// ---------------------------------------------------------------------------
extern "C" void kernel_launch(void* const* d_in, const int* in_sizes, int n_in,
                              void* d_out, int out_size, void* d_ws, size_t ws_size,
                              hipStream_t stream) {
    const float* x   = (const float*)d_in[0];
    const int*   ei  = (const int*)d_in[1];
    const float* W1  = (const float*)d_in[2];
    const float* b1  = (const float*)d_in[3];
    const float* Wl2 = (const float*)d_in[4];
    const float* bl2 = (const float*)d_in[5];
    const float* Wr2 = (const float*)d_in[6];
    const float* Wl3 = (const float*)d_in[7];
    const float* bl3 = (const float*)d_in[8];
    const float* Wr3 = (const float*)d_in[9];
    const float* Wl4 = (const float*)d_in[10];
    const float* bl4 = (const float*)d_in[11];
    const float* Wr4 = (const float*)d_in[12];
    const float* Wfc = (const float*)d_in[13];
    const float* bfc = (const float*)d_in[14];
    float* out = (float*)d_out;

    const int B = 32768;
    char* base = (char*)d_ws;
    float* gmat = (float*)base;
    bf16* Wt1 = (bf16*)(base + 4096);                  // FT [1024 x 64]
    bf16* Wt2 = Wt1 + 1024 * 64;                       // FT [1024 x 1024] interleaved
    bf16* Wt3 = Wt2 + 1024 * 1024;                     // FT [512 x 512]  interleaved
    bf16* Wt4 = Wt3 + 512 * 512;                       // FT [512 x 256]  interleaved
    char* sl  = (char*)(Wt4 + 512 * 256);
    size_t fixed = (size_t)(sl - base);

    // per-elem: R0 512B + R1 8192B + R2 4096B + ssq 48B = 12848 B
    int Bs = B;
    while (Bs > 512 && fixed + (size_t)Bs * 12848 > ws_size) Bs >>= 1;
    int nslice = B / Bs;
    int M = Bs * 4;

    bf16* R0 = (bf16*)sl;                       // xb FT [M,64]
    bf16* R1 = R0 + (size_t)Bs * 256;           // h1 FT [M,1024]; then h3_un FT [M,256]
    bf16* R2 = R1 + (size_t)Bs * 4096;          // h2_un FT [M,512]; then h4_un FT [M,256]
    float* ssqb = (float*)(R2 + (size_t)Bs * 2048);   // 3*M floats

    hipLaunchKernelGGL(k_setup, dim3(1), dim3(64), 0, stream, ei, gmat);
    hipLaunchKernelGGL(wtransF, dim3((1024 * 64 + 255) / 256), dim3(256), 0, stream,
                       W1, 64, 1024, Wt1);
    hipLaunchKernelGGL(wtransI, dim3((1024 * 1024 + 255) / 256), dim3(256), 0, stream,
                       Wl2, Wr2, 1024, 512, Wt2);
    hipLaunchKernelGGL(wtransI, dim3((512 * 512 + 255) / 256), dim3(256), 0, stream,
                       Wl3, Wr3, 512, 256, Wt3);
    hipLaunchKernelGGL(wtransI, dim3((512 * 256 + 255) / 256), dim3(256), 0, stream,
                       Wl4, Wr4, 256, 256, Wt4);

    for (int s = 0; s < nslice; s++) {
        const float* xs = x + (size_t)s * Bs * 256;
        hipLaunchKernelGGL(k_zero, dim3((3 * M / 4 + 255) / 256), dim3(256), 0, stream,
                           (float4*)ssqb, 3 * M / 4);
        hipLaunchKernelGGL(cast_x, dim3(Bs / 8), dim3(256), 0, stream,
                           (const float4*)xs, (bf16x8*)R0);
        // L1 GCN: h1 = relu(mix(x@W1) + b1)   [mode 1]  N=1024, K=64
        hipLaunchKernelGGL(gemm_mfma, dim3(4, M / 128), dim3(256), 0, stream,
                           R0, 64, Wt1, b1, R1, 1024, 1, gmat, (float*)nullptr);
        // L2 SAGE: h2_un (F=512) + ssq  [mode 2]  N=1024, K=1024
        hipLaunchKernelGGL(gemm_mfma, dim3(4, M / 128), dim3(256), 0, stream,
                           R1, 1024, Wt2, bl2, R2, 1024, 2, gmat + 16, ssqb);
        hipLaunchKernelGGL(norm_apply, dim3(M / 4), dim3(256), 0, stream,
                           (bf16x8*)R2, ssqb, 5);          // F=512 -> T=32 -> tsh=5
        // L3 SAGE: h3_un (F=256) into R1   N=512, K=512
        hipLaunchKernelGGL(gemm_mfma, dim3(2, M / 128), dim3(256), 0, stream,
                           R2, 512, Wt3, bl3, R1, 512, 2, gmat + 16, ssqb + M);
        hipLaunchKernelGGL(norm_apply, dim3(M / 8), dim3(256), 0, stream,
                           (bf16x8*)R1, ssqb + M, 4);      // F=256 -> T=16 -> tsh=4
        // L4 SAGE: h4_un (F=256) into R2   N=512, K=256
        hipLaunchKernelGGL(gemm_mfma, dim3(2, M / 128), dim3(256), 0, stream,
                           R1, 256, Wt4, bl4, R2, 512, 2, gmat + 16, ssqb + 2 * M);
        // FC + softmax with fused h4 norm+ReLU (FT input)
        hipLaunchKernelGGL(fc_softmax, dim3(Bs / 4), dim3(256), 0, stream,
                           (const bf16x8*)R2, ssqb + 2 * M, Wfc, bfc,
                           out + (size_t)s * Bs * 10);
    }
}